// Round 5
// baseline (73.978 us; speedup 1.0000x reference)
//
#include <hip/hip_runtime.h>
#include <cstdint>
#include <cstddef>

// Problem constants
#define NB    32
#define NC1   64
#define NC2   128
#define NE    4
#define NSLOT 5
#define HIN   64
#define WIN   64
#define HOUT  32
#define WOUT  32

// ws layout (float offsets)
#define GATEIN_OFF 0        // [32][64] f32
#define BIAS_OFF   2176     // [5][128] f32
#define GAMMA_OFF  2816     // [5][128] f32
#define BETA_OFF   3456     // [5][128] f32
#define WBF_OFF    4096     // bf16 frag table [5][9][4 wv][4 kk][64 lane][8]

typedef __bf16 bf16x8 __attribute__((ext_vector_type(8)));
typedef float  f32x16 __attribute__((ext_vector_type(16)));

// ---------------------------------------------------------------------------
// Kernel A (merged): blocks [0,1440): weight/bias repack into MFMA frag order
//   wfrag elem = slot*73728 + tap*8192 + wv*2048 + kk*512 + lane*8 + j
//     = W[slot][c2 = wv*32 + (lane&31)][c = kk*16 + (lane>>5)*8 + j][tap]
// blocks [1440,1952): gate_in[b][c] row means (one wave per (b,c) row).
// ---------------------------------------------------------------------------
__global__ void prep2_kernel(const float* __restrict__ x,
                             const float* __restrict__ expert_w,
                             const float* __restrict__ shared_w,
                             const float* __restrict__ expert_b,
                             const float* __restrict__ shared_b,
                             const float* __restrict__ eln_w,
                             const float* __restrict__ sln_w,
                             const float* __restrict__ eln_b,
                             const float* __restrict__ sln_b,
                             float* __restrict__ ws) {
    int bid = blockIdx.x;
    if (bid < 1440) {
        int i = bid * 256 + threadIdx.x;
        {
            int j    = i & 7;
            int l    = (i >> 3) & 63;
            int kk   = (i >> 9) & 3;
            int wv   = (i >> 11) & 3;
            int rest = i >> 13;
            int tap  = rest % 9;
            int e    = rest / 9;
            int c2 = wv * 32 + (l & 31);
            int c  = kk * 16 + (l >> 5) * 8 + j;
            float v;
            if (e < NE) v = expert_w[(((size_t)(e * NC2 + c2) * NC1 + c) * 9) + tap];
            else        v = shared_w[(((size_t)c2 * NC1 + c) * 9) + tap];
            ((__bf16*)(ws + WBF_OFF))[i] = (__bf16)v;
        }
        if (i < NSLOT * NC2) {
            int e = i >> 7, c2 = i & 127;
            ws[BIAS_OFF  + i] = (e < NE) ? expert_b[i] : shared_b[c2];
            ws[GAMMA_OFF + i] = (e < NE) ? eln_w[i]    : sln_w[c2];
            ws[BETA_OFF  + i] = (e < NE) ? eln_b[i]    : sln_b[c2];
        }
    } else {
        int row  = (bid - 1440) * 4 + (threadIdx.x >> 6);   // b*64 + c, 0..2047
        int lane = threadIdx.x & 63;
        const float* src = x + (size_t)row * (HIN * WIN);
        float s = 0.f;
        for (int i = lane * 4; i < HIN * WIN; i += 64 * 4) {
            float4 v = *(const float4*)(src + i);
            s += v.x + v.y + v.z + v.w;
        }
        #pragma unroll
        for (int off = 32; off >= 1; off >>= 1) s += __shfl_xor(s, off);
        if (lane == 0) ws[GATEIN_OFF + row] = s * (1.f / (HIN * WIN));
    }
}

// ---------------------------------------------------------------------------
// Kernel D: MFMA implicit-GEMM conv + LN + gated combine.
// Block = (b, hg), 768 threads = 12 waves = 3 slot-groups x 4 c2-tiles.
// Wave (sg, wv): slot sg in {s0, s1, shared}; c2 rows [wv*32,+32);
// 2 accumulators for h' = 2hg and 2hg+1 (rows r3 and r3+2 of the 5 staged).
// LDS xs[r][p][c] bf16, p = w_in+1, swizzle ps = (c>>3) ^ ((p>>1)&7).
// After conv: per-slot LN, then 3-way gated sum in an LDS out-tile (aliased
// over xs, which is dead), then one coalesced cooperative store.
// ---------------------------------------------------------------------------
#define XS_IDX(r, p, ps, c7) ((((r) * 65 + (p)) << 6) + ((ps) << 3) + (c7))

__global__ __launch_bounds__(768, 6) void fused_kernel(
        const float* __restrict__ x,
        const float* __restrict__ w_gate,
        const float* __restrict__ ws,
        float* __restrict__ out) {
    __shared__ __align__(16) unsigned char smem[5 * 65 * 64 * 2];  // 41600 B
    __shared__ float red[3 * 2 * 2 * 128];                          // 6144 B
    __shared__ float gsh[4];

    __bf16* xs = (__bf16*)smem;

    const int bid = blockIdx.x;             // 0..511
    const int b   = bid >> 4;
    const int hg  = bid & 15;
    const int tid = threadIdx.x;
    const int ln  = tid & 63;
    const int wid = tid >> 6;               // 0..11
    const int sg  = wid >> 2;               // slot group 0..2
    const int wv  = wid & 3;                // c2 tile
    const int cl  = ln & 31;
    const int hl  = ln >> 5;
    const int wbase = wv * 32;

    // ---- stage 5 input rows (hin = 4hg-1+r), coalesced ----
    for (int idx = tid; idx < 5 * 1024; idx += 768) {
        int r   = idx >> 10;
        int rem = idx & 1023;
        int c   = rem >> 4;
        int i4  = rem & 15;
        int hin = 4 * hg - 1 + r;
        float4 v = make_float4(0.f, 0.f, 0.f, 0.f);
        if (hin >= 0)
            v = *(const float4*)(x + (((size_t)b * NC1 + c) * HIN + hin) * WIN + i4 * 4);
        #pragma unroll
        for (int k = 0; k < 4; ++k) {
            int p  = i4 * 4 + k + 1;
            int ps = (c >> 3) ^ ((p >> 1) & 7);
            float f = (k == 0) ? v.x : (k == 1) ? v.y : (k == 2) ? v.z : v.w;
            xs[XS_IDX(r, p, ps, c & 7)] = (__bf16)f;
        }
    }
    if (tid >= 768 - 64) {   // last wave zeroes the p=0 pad column
        int l = tid & 63;
        #pragma unroll
        for (int r = 0; r < 5; ++r) xs[XS_IDX(r, 0, (l >> 3), l & 7)] = (__bf16)0.f;
    }

    // ---- wave 0: gating (top-2 softmax) while others stage ----
    if (tid < 64) {
        float gi = ws[GATEIN_OFF + b * NC1 + tid];
        float l[NE];
        #pragma unroll
        for (int e = 0; e < NE; ++e) {
            float p = gi * w_gate[tid * NE + e];
            #pragma unroll
            for (int off = 32; off >= 1; off >>= 1) p += __shfl_xor(p, off);
            l[e] = p;
        }
        if (tid == 0) {
            int i0 = 0; float v0 = l[0];
            #pragma unroll
            for (int e = 1; e < NE; ++e) if (l[e] > v0) { v0 = l[e]; i0 = e; }
            int i1 = -1; float v1 = -3.4e38f;
            #pragma unroll
            for (int e = 0; e < NE; ++e) if (e != i0 && l[e] > v1) { v1 = l[e]; i1 = e; }
            float e1 = expf(v1 - v0);
            float denom = 1.f + e1;
            gsh[0] = (float)i0; gsh[1] = 1.f / denom;
            gsh[2] = (float)i1; gsh[3] = e1 / denom;
        }
    }

    __syncthreads();

    // ---- this wave's slot + gate ----
    int slot; float g;
    if (sg == 0)      { slot = (int)gsh[0]; g = gsh[1]; }
    else if (sg == 1) { slot = (int)gsh[2]; g = gsh[3]; }
    else              { slot = 4;           g = 1.0f;   }

    // ---- init accumulators with bias ----
    const int rowbase = wbase + 4 * hl;
    f32x16 accA, accB;
    {
        const float4* bp = (const float4*)(ws + BIAS_OFF + slot * NC2 + rowbase);
        float4 b0 = bp[0], b1 = bp[2], b2 = bp[4], b3 = bp[6];
        accA[0]=b0.x; accA[1]=b0.y; accA[2]=b0.z; accA[3]=b0.w;
        accA[4]=b1.x; accA[5]=b1.y; accA[6]=b1.z; accA[7]=b1.w;
        accA[8]=b2.x; accA[9]=b2.y; accA[10]=b2.z; accA[11]=b2.w;
        accA[12]=b3.x; accA[13]=b3.y; accA[14]=b3.z; accA[15]=b3.w;
        accB = accA;
    }

    // ---- main loop: 9 taps x 4 kk; 1 A-load feeds 2 MFMAs (h'-pair) ----
    const __bf16* apb = (const __bf16*)(ws + WBF_OFF)
                        + (size_t)slot * 73728 + wv * 2048 + ln * 8;
    const int p_l = 2 * cl;
    #define MFMA(A, B, C) C = __builtin_amdgcn_mfma_f32_32x32x16_bf16(A, B, C, 0, 0, 0)
    #pragma unroll
    for (int r3 = 0; r3 < 3; ++r3) {
        #pragma unroll
        for (int kw = 0; kw < 3; ++kw) {
            const int tap = r3 * 3 + kw;
            const int p   = p_l + kw;
            const int swb = (p >> 1) & 7;
            const __bf16* ap = apb + tap * 8192;
            #pragma unroll
            for (int kk = 0; kk < 4; ++kk) {
                bf16x8 av = *(const bf16x8*)(ap + kk * 512);
                bf16x8 bA = *(const bf16x8*)&xs[XS_IDX(r3,     p, (2 * kk + hl) ^ swb, 0)];
                bf16x8 bB = *(const bf16x8*)&xs[XS_IDX(r3 + 2, p, (2 * kk + hl) ^ swb, 0)];
                MFMA(av, bA, accA);
                MFMA(av, bB, accB);
            }
        }
    }

    // ---- LN partials: red[((sg*2+t)*2+stat)*128 + c2col] ----
    #define PUT_RED(ACC, T)                                                       \
    {                                                                             \
        float sum = 0.f, sq = 0.f;                                                \
        _Pragma("unroll")                                                         \
        for (int i = 0; i < 16; ++i) { float a = ACC[i]; sum += a; sq += a * a; } \
        sum += __shfl_xor(sum, 32); sq += __shfl_xor(sq, 32);                     \
        if (ln < 32) {                                                            \
            red[((sg * 2 + (T)) * 2 + 0) * 128 + wbase + cl] = sum;               \
            red[((sg * 2 + (T)) * 2 + 1) * 128 + wbase + cl] = sq;                \
        }                                                                         \
    }
    PUT_RED(accA, 0)
    PUT_RED(accB, 1)
    __syncthreads();

    // ---- apply LN + gate to this wave's two tiles ----
    float vA[16], vB[16];
    float gm[16], bt[16];
    {
        const float4* gmp = (const float4*)(ws + GAMMA_OFF + slot * NC2 + rowbase);
        const float4* btp = (const float4*)(ws + BETA_OFF  + slot * NC2 + rowbase);
        float4 g0 = gmp[0], g1 = gmp[2], g2 = gmp[4], g3 = gmp[6];
        float4 t0 = btp[0], t1 = btp[2], t2 = btp[4], t3 = btp[6];
        gm[0]=g0.x;gm[1]=g0.y;gm[2]=g0.z;gm[3]=g0.w;gm[4]=g1.x;gm[5]=g1.y;gm[6]=g1.z;gm[7]=g1.w;
        gm[8]=g2.x;gm[9]=g2.y;gm[10]=g2.z;gm[11]=g2.w;gm[12]=g3.x;gm[13]=g3.y;gm[14]=g3.z;gm[15]=g3.w;
        bt[0]=t0.x;bt[1]=t0.y;bt[2]=t0.z;bt[3]=t0.w;bt[4]=t1.x;bt[5]=t1.y;bt[6]=t1.z;bt[7]=t1.w;
        bt[8]=t2.x;bt[9]=t2.y;bt[10]=t2.z;bt[11]=t2.w;bt[12]=t3.x;bt[13]=t3.y;bt[14]=t3.z;bt[15]=t3.w;
    }
    #define APPLY(ACC, OUT, T)                                                    \
    {                                                                             \
        float tot  = red[((sg * 2 + (T)) * 2 + 0) * 128 + 0 * 32 + cl]            \
                   + red[((sg * 2 + (T)) * 2 + 0) * 128 + 1 * 32 + cl]            \
                   + red[((sg * 2 + (T)) * 2 + 0) * 128 + 2 * 32 + cl]            \
                   + red[((sg * 2 + (T)) * 2 + 0) * 128 + 3 * 32 + cl];           \
        float totq = red[((sg * 2 + (T)) * 2 + 1) * 128 + 0 * 32 + cl]            \
                   + red[((sg * 2 + (T)) * 2 + 1) * 128 + 1 * 32 + cl]            \
                   + red[((sg * 2 + (T)) * 2 + 1) * 128 + 2 * 32 + cl]            \
                   + red[((sg * 2 + (T)) * 2 + 1) * 128 + 3 * 32 + cl];           \
        float mean = tot * (1.f / NC2);                                           \
        float var  = totq * (1.f / NC2) - mean * mean;                            \
        float rstd = rsqrtf(var + 1e-6f);                                         \
        _Pragma("unroll")                                                         \
        for (int i = 0; i < 16; ++i) {                                            \
            float nrm = (ACC[i] - mean) * rstd;                                   \
            OUT[i] = g * fmaf(gm[i], nrm, bt[i]);                                 \
        }                                                                         \
    }
    APPLY(accA, vA, 0)
    APPLY(accB, vB, 1)

    // ---- 3-way gated sum in LDS out-tile (aliases dead xs) ----
    float* ob = (float*)smem;   // [t][128 c2][32 w'] = 32768 B
    #define OB_WR(OP)                                                             \
    {                                                                             \
        _Pragma("unroll")                                                         \
        for (int i = 0; i < 16; ++i) {                                            \
            int c2 = rowbase + (i & 3) + 8 * (i >> 2);                            \
            ob[(0 * 128 + c2) * 32 + cl] OP vA[i];                                \
            ob[(1 * 128 + c2) * 32 + cl] OP vB[i];                                \
        }                                                                         \
    }
    if (sg == 0) OB_WR(=)
    __syncthreads();
    if (sg == 1) OB_WR(+=)
    __syncthreads();
    if (sg == 2) OB_WR(+=)
    __syncthreads();

    // ---- coalesced cooperative store: 2048 float4 ----
    for (int idx = tid; idx < 2048; idx += 768) {
        int t   = idx >> 10;
        int rem = idx & 1023;
        int c2  = rem >> 3;
        int q   = rem & 7;
        float4 v = *(const float4*)&ob[(t * 128 + c2) * 32 + q * 4];
        *(float4*)(out + (((size_t)b * NC2 + c2) * HOUT + 2 * hg + t) * WOUT + q * 4) = v;
    }
}

// ---------------------------------------------------------------------------
extern "C" void kernel_launch(void* const* d_in, const int* in_sizes, int n_in,
                              void* d_out, int out_size, void* d_ws, size_t ws_size,
                              hipStream_t stream) {
    const float* x        = (const float*)d_in[0];
    const float* w_gate   = (const float*)d_in[1];
    const float* expert_w = (const float*)d_in[2];
    const float* expert_b = (const float*)d_in[3];
    const float* eln_w    = (const float*)d_in[4];
    const float* eln_b    = (const float*)d_in[5];
    const float* shared_w = (const float*)d_in[6];
    const float* shared_b = (const float*)d_in[7];
    const float* sln_w    = (const float*)d_in[8];
    const float* sln_b    = (const float*)d_in[9];
    float* ws  = (float*)d_ws;
    float* out = (float*)d_out;

    // A: repack (blocks 0..1439) + gate_in means (blocks 1440..1951)
    prep2_kernel<<<1952, 256, 0, stream>>>(x, expert_w, shared_w, expert_b, shared_b,
                                           eln_w, sln_w, eln_b, sln_b, ws);
    // D: fused gating + conv + LN + combine
    fused_kernel<<<NB * 16, 768, 0, stream>>>(x, w_gate, ws, out);
}

// Round 6
// 47.261 us; speedup vs baseline: 1.5653x; 1.5653x over previous
//
#include <hip/hip_runtime.h>
#include <cstdint>
#include <cstddef>

// Problem constants
#define NB    32
#define NC1   64
#define NC2   128
#define NE    4
#define NSLOT 5
#define HIN   64
#define WIN   64
#define HOUT  32
#define WOUT  32

// ws layout (float offsets)
#define GATEIN_OFF 0        // [32][64] f32
#define BIAS_OFF   2176     // [5][128] f32
#define GAMMA_OFF  2816     // [5][128] f32
#define BETA_OFF   3456     // [5][128] f32
#define WBF_OFF    4096     // bf16 frag table [5][9][4 wv][4 kk][64 lane][8]

typedef __bf16 bf16x8 __attribute__((ext_vector_type(8)));
typedef float  f32x16 __attribute__((ext_vector_type(16)));

#define GLOAD_LDS16(G, L)                                                        \
    __builtin_amdgcn_global_load_lds(                                            \
        (const __attribute__((address_space(1))) void*)(G),                      \
        (__attribute__((address_space(3))) void*)(L), 16, 0, 0)

// ---------------------------------------------------------------------------
// Kernel A (merged): blocks [0,1440): weight/bias repack into MFMA frag order
//   wfrag elem = slot*73728 + tap*8192 + wv*2048 + kk*512 + lane*8 + j
//     = W[slot][c2 = wv*32 + (lane&31)][c = kk*16 + (lane>>5)*8 + j][tap]
// blocks [1440,1952): gate_in[b][c] row means (one wave per (b,c) row).
// ---------------------------------------------------------------------------
__global__ void prep2_kernel(const float* __restrict__ x,
                             const float* __restrict__ expert_w,
                             const float* __restrict__ shared_w,
                             const float* __restrict__ expert_b,
                             const float* __restrict__ shared_b,
                             const float* __restrict__ eln_w,
                             const float* __restrict__ sln_w,
                             const float* __restrict__ eln_b,
                             const float* __restrict__ sln_b,
                             float* __restrict__ ws) {
    int bid = blockIdx.x;
    if (bid < 1440) {
        int i = bid * 256 + threadIdx.x;
        {
            int j    = i & 7;
            int l    = (i >> 3) & 63;
            int kk   = (i >> 9) & 3;
            int wv   = (i >> 11) & 3;
            int rest = i >> 13;
            int tap  = rest % 9;
            int e    = rest / 9;
            int c2 = wv * 32 + (l & 31);
            int c  = kk * 16 + (l >> 5) * 8 + j;
            float v;
            if (e < NE) v = expert_w[(((size_t)(e * NC2 + c2) * NC1 + c) * 9) + tap];
            else        v = shared_w[(((size_t)c2 * NC1 + c) * 9) + tap];
            ((__bf16*)(ws + WBF_OFF))[i] = (__bf16)v;
        }
        if (i < NSLOT * NC2) {
            int e = i >> 7, c2 = i & 127;
            ws[BIAS_OFF  + i] = (e < NE) ? expert_b[i] : shared_b[c2];
            ws[GAMMA_OFF + i] = (e < NE) ? eln_w[i]    : sln_w[c2];
            ws[BETA_OFF  + i] = (e < NE) ? eln_b[i]    : sln_b[c2];
        }
    } else {
        int row  = (bid - 1440) * 4 + (threadIdx.x >> 6);   // b*64 + c
        int lane = threadIdx.x & 63;
        const float* src = x + (size_t)row * (HIN * WIN);
        float s = 0.f;
        for (int i = lane * 4; i < HIN * WIN; i += 64 * 4) {
            float4 v = *(const float4*)(src + i);
            s += v.x + v.y + v.z + v.w;
        }
        #pragma unroll
        for (int off = 32; off >= 1; off >>= 1) s += __shfl_xor(s, off);
        if (lane == 0) ws[GATEIN_OFF + row] = s * (1.f / (HIN * WIN));
    }
}

// ---------------------------------------------------------------------------
// Kernel D: MFMA implicit-GEMM conv + LN + gated combine, DMA-staged weights.
// Block = (b, hg), 512 threads = 8 waves = 2 h'-groups (tg) x 4 c2-tiles (wv).
// Wave (tg, wv): 3 slots x h'=2hg+tg, c2 rows [wv*32,+32) -> 3 accumulators.
// Weights: per tap, 48 KB (3 slots x 16 KB frag blocks) DMA'd via
// global_load_lds into a double-buffered LDS region (linear lane order, so
// the wave-uniform-base constraint is satisfied); A-frags then are
// conflict-free linear ds_read_b128. Stage of tap t+1 issued before compute
// of tap t; the per-tap __syncthreads drains it after compute.
// LDS: xs 41600 B | wbuf 2x49152 B | red 6144 B  = 146048 B -> 1 block/CU.
// ---------------------------------------------------------------------------
#define XS_IDX(r, p, ps, c7) ((((r) * 65 + (p)) << 6) + ((ps) << 3) + (c7))
#define XS_BYTES   41600
#define WBUF_ELEMS 24576    // bf16 elems per buffer (48 KB)

__global__ __launch_bounds__(512, 2) void fused_kernel(
        const float* __restrict__ x,
        const float* __restrict__ w_gate,
        const float* __restrict__ ws,
        float* __restrict__ out) {
    __shared__ __align__(16) unsigned char smem[XS_BYTES + 2 * 49152 + 6144];
    __bf16* xs  = (__bf16*)smem;
    __bf16* wb  = (__bf16*)(smem + XS_BYTES);
    float*  red = (float*)(smem + XS_BYTES + 2 * 49152);

    const int bid = blockIdx.x;             // 0..511
    const int b   = bid >> 4;
    const int hg  = bid & 15;
    const int tid = threadIdx.x;
    const int ln  = tid & 63;
    const int wv8 = tid >> 6;               // 0..7
    const int tg  = wv8 >> 2;               // h'-half
    const int wv  = wv8 & 3;                // c2 tile
    const int cl  = ln & 31;
    const int hl  = ln >> 5;
    const int wbase = wv * 32;

    // ---- gating: every wave computes top-2 softmax redundantly ----
    int s0, s1; float ga, gb;
    {
        float gi = ws[GATEIN_OFF + b * NC1 + ln];
        float l[NE];
        #pragma unroll
        for (int e = 0; e < NE; ++e) {
            float p = gi * w_gate[ln * NE + e];
            #pragma unroll
            for (int off = 32; off >= 1; off >>= 1) p += __shfl_xor(p, off);
            l[e] = p;
        }
        int i0 = 0; float v0 = l[0];
        #pragma unroll
        for (int e = 1; e < NE; ++e) if (l[e] > v0) { v0 = l[e]; i0 = e; }
        int i1 = -1; float v1 = -3.4e38f;
        #pragma unroll
        for (int e = 0; e < NE; ++e) if (e != i0 && l[e] > v1) { v1 = l[e]; i1 = e; }
        float e1 = expf(v1 - v0);
        float denom = 1.f + e1;
        s0 = i0; ga = 1.f / denom;
        s1 = i1; gb = e1 / denom;
    }

    // ---- weight DMA stage: 48 chunks of 1KB, 6 per wave ----
    const __bf16* wtab = (const __bf16*)(ws + WBF_OFF);
    #define ISSUE_W(TAP, BUF)                                                     \
    {                                                                             \
        _Pragma("unroll")                                                         \
        for (int i = 0; i < 6; ++i) {                                             \
            int chunk = wv8 * 6 + i;                /* 0..47, wave-uniform */     \
            int si    = chunk >> 4;                 /* slot idx 0..2 */           \
            int off   = (chunk & 15) << 9;          /* elem offset in 16KB */     \
            int sl    = (si == 0) ? s0 : ((si == 1) ? s1 : 4);                    \
            const __bf16* g = wtab + (size_t)sl * 73728 + (TAP) * 8192 + off + ln * 8; \
            __bf16* d = wb + (BUF) * WBUF_ELEMS + si * 8192 + off;                \
            GLOAD_LDS16(g, d);                                                    \
        }                                                                         \
    }
    ISSUE_W(0, 0)

    // ---- x stage: 5 rows (hin = 4hg-1+r), transpose+bf16, swizzled ----
    #pragma unroll
    for (int r = 0; r < 5; ++r) {
        const int hin = 4 * hg - 1 + r;
        #pragma unroll
        for (int pass = 0; pass < 2; ++pass) {
            int idx = (pass << 9) + tid;    // 0..1023
            int c   = idx >> 4;
            int i4  = idx & 15;
            float4 v = make_float4(0.f, 0.f, 0.f, 0.f);
            if (hin >= 0)
                v = *(const float4*)(x + (((size_t)b * NC1 + c) * HIN + hin) * WIN + i4 * 4);
            #pragma unroll
            for (int k = 0; k < 4; ++k) {
                int p  = i4 * 4 + k + 1;
                int ps = (c >> 3) ^ ((p >> 1) & 7);
                float f = (k == 0) ? v.x : (k == 1) ? v.y : (k == 2) ? v.z : v.w;
                xs[XS_IDX(r, p, ps, c & 7)] = (__bf16)f;
            }
        }
    }
    if (tid < 64) {   // zero left-pad column p=0
        #pragma unroll
        for (int r = 0; r < 5; ++r) xs[XS_IDX(r, 0, (tid >> 3), tid & 7)] = (__bf16)0.f;
    }

    // ---- init 3 accumulators with bias ----
    const int rowbase = wbase + 4 * hl;
    f32x16 acc0, acc1, acc2;
    #define INIT_ACC(ACC, SID)                                                  \
    {                                                                           \
        const float4* bp = (const float4*)(ws + BIAS_OFF + (SID) * NC2 + rowbase); \
        float4 b0 = bp[0], b1 = bp[2], b2 = bp[4], b3 = bp[6];                  \
        ACC[0]=b0.x; ACC[1]=b0.y; ACC[2]=b0.z; ACC[3]=b0.w;                     \
        ACC[4]=b1.x; ACC[5]=b1.y; ACC[6]=b1.z; ACC[7]=b1.w;                     \
        ACC[8]=b2.x; ACC[9]=b2.y; ACC[10]=b2.z; ACC[11]=b2.w;                   \
        ACC[12]=b3.x; ACC[13]=b3.y; ACC[14]=b3.z; ACC[15]=b3.w;                 \
    }
    INIT_ACC(acc0, s0) INIT_ACC(acc1, s1) INIT_ACC(acc2, 4)

    __syncthreads();   // x + tap0 weights resident

    // ---- main loop: 9 taps; stage t+1 while computing t ----
    #define MFMA(A, B, C) C = __builtin_amdgcn_mfma_f32_32x32x16_bf16(A, B, C, 0, 0, 0)
    const int p_l = 2 * cl;
    #pragma unroll
    for (int t = 0; t < 9; ++t) {
        if (t < 8) { ISSUE_W(t + 1, (t + 1) & 1) }
        const int r3  = t / 3;
        const int kw  = t % 3;
        const int r   = r3 + 2 * tg;
        const int p   = p_l + kw;
        const int swb = (p >> 1) & 7;
        const __bf16* wbc = wb + (t & 1) * WBUF_ELEMS + wv * 2048 + ln * 8;
        #pragma unroll
        for (int kk = 0; kk < 4; ++kk) {
            bf16x8 bb = *(const bf16x8*)&xs[XS_IDX(r, p, (2 * kk + hl) ^ swb, 0)];
            bf16x8 a0 = *(const bf16x8*)(wbc + 0 * 8192 + kk * 512);
            bf16x8 a1 = *(const bf16x8*)(wbc + 1 * 8192 + kk * 512);
            bf16x8 a2 = *(const bf16x8*)(wbc + 2 * 8192 + kk * 512);
            MFMA(a0, bb, acc0);
            MFMA(a1, bb, acc1);
            MFMA(a2, bb, acc2);
        }
        __syncthreads();   // drains t+1 DMA; frees buf (t&1) for t+2
    }

    // ---- LN partials: red[((si*2+tg)*2+stat)*128 + c2col] ----
    #define PUT_RED(ACC, SI)                                                      \
    {                                                                             \
        float sum = 0.f, sq = 0.f;                                                \
        _Pragma("unroll")                                                         \
        for (int i = 0; i < 16; ++i) { float a = ACC[i]; sum += a; sq += a * a; } \
        sum += __shfl_xor(sum, 32); sq += __shfl_xor(sq, 32);                     \
        if (ln < 32) {                                                            \
            red[(((SI) * 2 + tg) * 2 + 0) * 128 + wbase + cl] = sum;              \
            red[(((SI) * 2 + tg) * 2 + 1) * 128 + wbase + cl] = sq;               \
        }                                                                         \
    }
    PUT_RED(acc0, 0)
    PUT_RED(acc1, 1)
    PUT_RED(acc2, 2)
    __syncthreads();

    float fin[16];
    #pragma unroll
    for (int i = 0; i < 16; ++i) fin[i] = 0.f;

    #define APPLY(ACC, SI, SID, G)                                                \
    {                                                                             \
        float tot = 0.f, totq = 0.f;                                              \
        _Pragma("unroll")                                                         \
        for (int w = 0; w < 4; ++w) {                                             \
            tot  += red[(((SI) * 2 + tg) * 2 + 0) * 128 + w * 32 + cl];           \
            totq += red[(((SI) * 2 + tg) * 2 + 1) * 128 + w * 32 + cl];           \
        }                                                                         \
        float mean = tot * (1.f / NC2);                                           \
        float var  = totq * (1.f / NC2) - mean * mean;                            \
        float rstd = rsqrtf(var + 1e-6f);                                         \
        const float4* gmp = (const float4*)(ws + GAMMA_OFF + (SID) * NC2 + rowbase); \
        const float4* btp = (const float4*)(ws + BETA_OFF  + (SID) * NC2 + rowbase); \
        float4 g0 = gmp[0], g1 = gmp[2], g2 = gmp[4], g3 = gmp[6];                \
        float4 t0 = btp[0], t1 = btp[2], t2 = btp[4], t3 = btp[6];                \
        float gm[16] = {g0.x,g0.y,g0.z,g0.w, g1.x,g1.y,g1.z,g1.w,                 \
                        g2.x,g2.y,g2.z,g2.w, g3.x,g3.y,g3.z,g3.w};                \
        float bt[16] = {t0.x,t0.y,t0.z,t0.w, t1.x,t1.y,t1.z,t1.w,                 \
                        t2.x,t2.y,t2.z,t2.w, t3.x,t3.y,t3.z,t3.w};                \
        _Pragma("unroll")                                                         \
        for (int i = 0; i < 16; ++i) {                                            \
            float nrm = (ACC[i] - mean) * rstd;                                   \
            fin[i] = fmaf((G), fmaf(gm[i], nrm, bt[i]), fin[i]);                  \
        }                                                                         \
    }
    APPLY(acc0, 0, s0, ga)
    APPLY(acc1, 1, s1, gb)
    APPLY(acc2, 2, 4, 1.0f)

    // ---- write fin to LDS out-tile (aliases dead wbuf), then coalesced store ----
    float* ob = (float*)(smem + XS_BYTES);   // [tg][128 c2][32 w'] = 32768 B
    #pragma unroll
    for (int i = 0; i < 16; ++i) {
        int c2 = rowbase + (i & 3) + 8 * (i >> 2);
        ob[(tg * 128 + c2) * 32 + cl] = fin[i];
    }
    __syncthreads();
    for (int idx = tid; idx < 2048; idx += 512) {
        int t2  = idx >> 10;
        int rem = idx & 1023;
        int c2  = rem >> 3;
        int q   = rem & 7;
        float4 v = *(const float4*)&ob[(t2 * 128 + c2) * 32 + q * 4];
        *(float4*)(out + (((size_t)b * NC2 + c2) * HOUT + 2 * hg + t2) * WOUT + q * 4) = v;
    }
}

// ---------------------------------------------------------------------------
extern "C" void kernel_launch(void* const* d_in, const int* in_sizes, int n_in,
                              void* d_out, int out_size, void* d_ws, size_t ws_size,
                              hipStream_t stream) {
    const float* x        = (const float*)d_in[0];
    const float* w_gate   = (const float*)d_in[1];
    const float* expert_w = (const float*)d_in[2];
    const float* expert_b = (const float*)d_in[3];
    const float* eln_w    = (const float*)d_in[4];
    const float* eln_b    = (const float*)d_in[5];
    const float* shared_w = (const float*)d_in[6];
    const float* shared_b = (const float*)d_in[7];
    const float* sln_w    = (const float*)d_in[8];
    const float* sln_b    = (const float*)d_in[9];
    float* ws  = (float*)d_ws;
    float* out = (float*)d_out;

    prep2_kernel<<<1952, 256, 0, stream>>>(x, expert_w, shared_w, expert_b, shared_b,
                                           eln_w, sln_w, eln_b, sln_b, ws);
    fused_kernel<<<NB * 16, 512, 0, stream>>>(x, w_gate, ws, out);
}